// Round 4
// baseline (184.277 us; speedup 1.0000x reference)
//
#include <hip/hip_runtime.h>
#include <hip/hip_bf16.h>
#include <cstdint>
#include <cstddef>

#define DIM   1024
#define NH    16
#define HD    64
#define BB    4
#define TT    2048

typedef __attribute__((ext_vector_type(8))) short bf16x8;
typedef __attribute__((ext_vector_type(4))) short bf16x4;
typedef __attribute__((ext_vector_type(4))) float f32x4;
typedef __attribute__((ext_vector_type(4))) unsigned short u16x4;
typedef unsigned short u16;
typedef unsigned int u32;

#define NEG_INF (-__builtin_inff())
#define QSCALE 0.18033688011110543f  // 0.125 * log2(e): softmax becomes exp2
#define AS1 __attribute__((address_space(1)))
#define AS3 __attribute__((address_space(3)))

static __device__ __forceinline__ u16 f2bf(float f) {
  union { float f; unsigned u; } v; v.f = f;
  return (u16)((v.u + 0x7FFFu + ((v.u >> 16) & 1u)) >> 16);
}

static __device__ __forceinline__ u16 bfbits(float a) {
  union { __hip_bfloat16 h; u16 u; } c; c.h = __float2bfloat16(a); return c.u;
}
static __device__ __forceinline__ u32 pk_bf16(float a, float b) {
  return (u32)bfbits(a) | ((u32)bfbits(b) << 16);
}

static __device__ __forceinline__ float exp2_fast(float x) {
  float r;
  asm("v_exp_f32 %0, %1" : "=v"(r) : "v"(x));
  return r;
}

// HW transpose read: lane l receives column (l&15) of the 4x16 bf16 tile.
static __device__ __forceinline__ bf16x4 tr16(u32 byte_addr) {
  bf16x4 d;
  asm volatile("ds_read_b64_tr_b16 %0, %1" : "=v"(d) : "v"(byte_addr));
  return d;
}

// ---------------- elementwise f32 -> bf16 ----------------
__global__ __launch_bounds__(256) void k_cvt(const float* __restrict__ in,
                                             u16* __restrict__ out, int n4) {
  int i = blockIdx.x * 256 + threadIdx.x;
  if (i >= n4) return;
  float4 v = reinterpret_cast<const float4*>(in)[i];
  u16x4 o = { f2bf(v.x), f2bf(v.y), f2bf(v.z), f2bf(v.w) };
  *reinterpret_cast<u16x4*>(out + (size_t)i * 4) = o;
}

// ---------------- transpose f32[R][C] -> bf16[C][R] ----------------
__global__ __launch_bounds__(256) void k_transpose(const float* __restrict__ in,
                                                   u16* __restrict__ out,
                                                   int R, int C) {
  __shared__ float tile[32][33];
  int bx = blockIdx.x * 32;  // C dim
  int by = blockIdx.y * 32;  // R dim
  int tx = threadIdx.x & 31, ty = threadIdx.x >> 5;  // ty: 0..7
  #pragma unroll
  for (int i = 0; i < 32; i += 8)
    tile[ty + i][tx] = in[(size_t)(by + ty + i) * C + bx + tx];
  __syncthreads();
  #pragma unroll
  for (int i = 0; i < 32; i += 8)
    out[(size_t)(bx + ty + i) * R + by + tx] = f2bf(tile[tx][ty + i]);
}

// ======== 256x256 8-phase GEMM (T2+T3+T4+T5): C = A * Bt^T + bias ========
// BK=64, 8 waves (2M x 4N), 512 thr, 128KiB LDS. Half-tile = 128 rows x 64 k,
// stored [ksub][row][32] (64B rows) with st_16x32 swizzle byte^=((byte>>9)&1)<<5,
// applied as inverse-swizzled global source + swizzled ds_read (linear LDS dest).
// Per K-tile 4 phases; stages of tile t+2 issued after region death (B after P1,
// A after P2); counted vmcnt(8) once per tile; raw s_barrier; setprio on MFMA.
template <int OUT_BF16>
__global__ __launch_bounds__(512, 2) void k_gemm256(const u16* __restrict__ A,
                                                    const u16* __restrict__ Bt,
                                                    const float* __restrict__ bias,
                                                    u16* __restrict__ Cb,
                                                    float* __restrict__ Cf,
                                                    int M, int N, int K,
                                                    int scale_cols, float scale,
                                                    int nbx) {
  __shared__ __align__(16) u16 lds[2][2][2][8192];  // [buf][A/B][half][16KB/2]

  const int tid = threadIdx.x;
  // bijective XCD swizzle (m204)
  const int nwg = gridDim.x;
  const int q = nwg >> 3, rm = nwg & 7;
  const int xcd = blockIdx.x & 7, lidx = blockIdx.x >> 3;
  const int swz = (xcd < rm ? xcd * (q + 1) : rm * (q + 1) + (xcd - rm) * q) + lidx;
  const int m0 = (swz / nbx) * 256, n0 = (swz % nbx) * 256;

  const int w = tid >> 6, lane = tid & 63;
  const int g = lane >> 4, r = lane & 15;
  const int wm = w >> 2, wn = w & 3;

  f32x4 acc[8][4] = {};
  const int KT = K >> 6;

  // stage one 128x64 half-tile (2 x 16B chunks per thread)
  auto stageA = [&](int buf, int h, int kt) {
    char* base = (char*)&lds[buf][0][h][0];
    #pragma unroll
    for (int i = 0; i < 2; ++i) {
      int o = (tid + i * 512) * 16;
      int l = o ^ (((o >> 9) & 1) << 5);
      int row = (l >> 6) & 127, ks = l >> 13, kb = l & 63;
      const u16* gp = A + (size_t)(m0 + h * 128 + row) * K + kt * 64 + ks * 32 + (kb >> 1);
      __builtin_amdgcn_global_load_lds((const AS1 void*)gp, (AS3 void*)(base + o), 16, 0, 0);
    }
  };
  auto stageB = [&](int buf, int h, int kt) {
    char* base = (char*)&lds[buf][1][h][0];
    #pragma unroll
    for (int i = 0; i < 2; ++i) {
      int o = (tid + i * 512) * 16;
      int l = o ^ (((o >> 9) & 1) << 5);
      int row = (l >> 6) & 127, ks = l >> 13, kb = l & 63;
      const u16* gp = Bt + (size_t)(n0 + h * 128 + row) * K + kt * 64 + ks * 32 + (kb >> 1);
      __builtin_amdgcn_global_load_lds((const AS1 void*)gp, (AS3 void*)(base + o), 16, 0, 0);
    }
  };

  auto ldA = [&](int buf, int qm, bf16x8 (&a)[4][2]) {
    const char* base = (const char*)&lds[buf][0][wm][0];
    #pragma unroll
    for (int f = 0; f < 4; ++f)
      #pragma unroll
      for (int ks = 0; ks < 2; ++ks) {
        int l = ks * 8192 + (qm * 64 + f * 16 + r) * 64 + g * 16;
        int ph = l ^ (((l >> 9) & 1) << 5);
        a[f][ks] = *(const bf16x8*)(base + ph);
      }
  };
  auto ldB = [&](int buf, int qn, bf16x8 (&bb)[2][2]) {
    const char* base = (const char*)&lds[buf][1][wn >> 1][0];
    #pragma unroll
    for (int c = 0; c < 2; ++c)
      #pragma unroll
      for (int ks = 0; ks < 2; ++ks) {
        int l = ks * 8192 + ((wn & 1) * 64 + qn * 32 + c * 16 + r) * 64 + g * 16;
        int ph = l ^ (((l >> 9) & 1) << 5);
        bb[c][ks] = *(const bf16x8*)(base + ph);
      }
  };
  auto mfma16 = [&](bf16x8 (&a)[4][2], bf16x8 (&bb)[2][2], int rf0, int cf0) {
    __builtin_amdgcn_s_setprio(1);
    #pragma unroll
    for (int f = 0; f < 4; ++f)
      #pragma unroll
      for (int c = 0; c < 2; ++c)
        #pragma unroll
        for (int ks = 0; ks < 2; ++ks)
          acc[rf0 + f][cf0 + c] = __builtin_amdgcn_mfma_f32_16x16x32_bf16(
              a[f][ks], bb[c][ks], acc[rf0 + f][cf0 + c], 0, 0, 0);
    __builtin_amdgcn_s_setprio(0);
  };

  // prologue: tiles 0 and 1 fully staged (8 loads each per thread)
  stageA(0, 0, 0); stageA(0, 1, 0); stageB(0, 0, 0); stageB(0, 1, 0);
  stageA(1, 0, 1); stageA(1, 1, 1); stageB(1, 0, 1); stageB(1, 1, 1);
  asm volatile("s_waitcnt vmcnt(8)" ::: "memory");   // tile 0 landed
  __builtin_amdgcn_s_barrier();

  bf16x8 af[4][2], b0[2][2], b1[2][2];
  for (int kt = 0; kt < KT; ++kt) {
    const int buf = kt & 1;
    const bool st = (kt + 2 < KT);
    // P0: read A[qm0] + B[qn0]
    ldA(buf, 0, af);
    ldB(buf, 0, b0);
    __builtin_amdgcn_s_barrier();
    mfma16(af, b0, 0, 0);
    __builtin_amdgcn_s_barrier();
    // P1: read B[qn1]
    ldB(buf, 1, b1);
    __builtin_amdgcn_s_barrier();
    mfma16(af, b1, 0, 2);
    __builtin_amdgcn_s_barrier();
    // P2: read A[qm1]; stage B(t+2) (B regions dead after P1)
    ldA(buf, 1, af);
    if (st) { stageB(buf, 0, kt + 2); stageB(buf, 1, kt + 2); }
    __builtin_amdgcn_s_barrier();
    mfma16(af, b1, 4, 2);
    __builtin_amdgcn_s_barrier();
    // P3: stage A(t+2) (A regions dead after P2)
    if (st) { stageA(buf, 0, kt + 2); stageA(buf, 1, kt + 2); }
    mfma16(af, b0, 4, 0);
    if (st) asm volatile("s_waitcnt vmcnt(8)" ::: "memory");
    else    asm volatile("s_waitcnt vmcnt(0)" ::: "memory");
    __builtin_amdgcn_s_barrier();
  }

  // epilogue: row = m0+wm*128+rf*16+g*4+e, col = n0+wn*64+cf*16+r
  #pragma unroll
  for (int cf = 0; cf < 4; ++cf) {
    int col = n0 + wn * 64 + cf * 16 + r;
    float bv = bias[col];
    float sc = (col < scale_cols) ? scale : 1.0f;
    #pragma unroll
    for (int rf = 0; rf < 8; ++rf) {
      #pragma unroll
      for (int e = 0; e < 4; ++e) {
        int row = m0 + wm * 128 + rf * 16 + g * 4 + e;
        float val = (acc[rf][cf][e] + bv) * sc;
        if (OUT_BF16) Cb[(size_t)row * N + col] = f2bf(val);
        else          Cf[(size_t)row * N + col] = val;
      }
    }
  }
}

// ---------------- 128x128 2-phase GEMM (control / GEMM2) ----------------
template <int OUT_BF16>
__global__ __launch_bounds__(256, 2) void k_gemm(const u16* __restrict__ A,
                                                 const u16* __restrict__ Bt,
                                                 const float* __restrict__ bias,
                                                 u16* __restrict__ Cb,
                                                 float* __restrict__ Cf,
                                                 int M, int N, int K,
                                                 int scale_cols, float scale) {
  __shared__ __align__(16) u16 lA[2][128 * 32];
  __shared__ __align__(16) u16 lB[2][128 * 32];
  const int tid = threadIdx.x;
  const int m0 = blockIdx.y * 128, n0 = blockIdx.x * 128;
  const int lane = tid & 63;
  const int w = tid >> 6;
  const int g = lane >> 4, r = lane & 15;
  const int wm = w >> 1, wn = w & 1;

  f32x4 acc[4][4] = {};

  const int KT = K >> 5;

  auto stage = [&](int buf, int kt) {
    const int k0 = kt << 5;
    #pragma unroll
    for (int i = 0; i < 2; ++i) {
      int c = tid + 256 * i;
      int row = c >> 2, col = (c & 3) << 3;
      const u16* gp = A + (size_t)(m0 + row) * K + k0 + col;
      u16* lp = &lA[buf][c << 3];
      __builtin_amdgcn_global_load_lds((const AS1 void*)gp, (AS3 void*)lp, 16, 0, 0);
    }
    #pragma unroll
    for (int i = 0; i < 2; ++i) {
      int c = tid + 256 * i;
      int row = c >> 2, col = (c & 3) << 3;
      const u16* gp = Bt + (size_t)(n0 + row) * K + k0 + col;
      u16* lp = &lB[buf][c << 3];
      __builtin_amdgcn_global_load_lds((const AS1 void*)gp, (AS3 void*)lp, 16, 0, 0);
    }
  };

  stage(0, 0);
  asm volatile("s_waitcnt vmcnt(0)" ::: "memory");
  __syncthreads();

  int cur = 0;
  for (int kt = 0; kt < KT; ++kt) {
    if (kt + 1 < KT) stage(cur ^ 1, kt + 1);
    bf16x8 af[4], bfr[4];
    #pragma unroll
    for (int m = 0; m < 4; ++m)
      af[m] = *(const bf16x8*)&lA[cur][(wm * 64 + m * 16 + r) * 32 + g * 8];
    #pragma unroll
    for (int n = 0; n < 4; ++n)
      bfr[n] = *(const bf16x8*)&lB[cur][(wn * 64 + n * 16 + r) * 32 + g * 8];
    #pragma unroll
    for (int m = 0; m < 4; ++m)
      #pragma unroll
      for (int n = 0; n < 4; ++n)
        acc[m][n] = __builtin_amdgcn_mfma_f32_16x16x32_bf16(af[m], bfr[n], acc[m][n], 0, 0, 0);
    asm volatile("s_waitcnt vmcnt(0)" ::: "memory");
    __syncthreads();
    cur ^= 1;
  }

  #pragma unroll
  for (int n = 0; n < 4; ++n) {
    int col = n0 + wn * 64 + n * 16 + r;
    float bv = bias[col];
    float sc = (col < scale_cols) ? scale : 1.0f;
    #pragma unroll
    for (int m = 0; m < 4; ++m) {
      #pragma unroll
      for (int reg = 0; reg < 4; ++reg) {
        int row = m0 + wm * 64 + m * 16 + g * 4 + reg;
        float val = (acc[m][n][reg] + bv) * sc;
        if (OUT_BF16) Cb[(size_t)row * N + col] = f2bf(val);
        else          Cf[(size_t)row * N + col] = val;
      }
    }
  }
}

// ---------------- causal flash attention ----------------
#define KVB 64
#define LBUF16 8192   // u16 elems per buffer: K 4096 + V 4096

__global__ __launch_bounds__(256, 2) void k_attn(const u16* __restrict__ qkv,
                                                 u16* __restrict__ aout) {
  __shared__ __align__(16) u16 smem[2 * LBUF16];

  const int bid = blockIdx.x;
  const int swz = (bid & 7) * 64 + (bid >> 3);   // XCD swizzle (512 % 8 == 0)
  const int bh = swz >> 3;
  const int p = swz & 7;
  const int b = bh >> 4, h = bh & 15;
  const int tid = threadIdx.x, w = tid >> 6, lane = tid & 63;
  const int g = lane >> 4, r = lane & 15;

  const u32 vls0 = (u32)(uintptr_t)(AS3 u16*)(smem + 4096);
  const u32 vls1 = (u32)(uintptr_t)(AS3 u16*)(smem + LBUF16 + 4096);

  auto issueKV = [&](int buf, int t) {
    const int kv0 = t * KVB;
    u16* kb = &smem[buf * LBUF16];
    u16* vb = &smem[buf * LBUF16 + 4096];
    #pragma unroll
    for (int i = 0; i < 2; ++i) {
      int s = tid + 256 * i;
      int row = s >> 3, c8 = s & 7;
      int colg = c8 ^ (row & 7);   // pre-swizzled source, linear LDS dest
      const u16* gp = qkv + ((size_t)(b * TT) + kv0 + row) * (3 * DIM) + DIM + h * HD + colg * 8;
      __builtin_amdgcn_global_load_lds((const AS1 void*)gp,
                                       (AS3 void*)(kb + (size_t)s * 8), 16, 0, 0);
    }
    #pragma unroll
    for (int i = 0; i < 2; ++i) {
      int s = tid + 256 * i;
      int key = (s >> 1) & 63;
      int c = ((s >> 7) << 1) | (s & 1);
      const u16* gp = qkv + ((size_t)(b * TT) + kv0 + key) * (3 * DIM) + 2 * DIM + h * HD + c * 8;
      __builtin_amdgcn_global_load_lds((const AS1 void*)gp,
                                       (AS3 void*)(vb + (size_t)s * 8), 16, 0, 0);
    }
  };

  for (int half = 0; half < 2; ++half) {
    const int qt = half ? p : (15 - p);
    const int qbase = qt * 128;
    const int nt = 2 * qt + 2;
    const int qg0 = qbase + w * 16 + r;

    bf16x8 qf[2][2];
    #pragma unroll
    for (int qb = 0; qb < 2; ++qb) {
      const u16* qp = qkv + ((size_t)(b * TT) + qg0 + qb * 64) * (3 * DIM) + h * HD;
      #pragma unroll
      for (int kk = 0; kk < 2; ++kk)
        qf[qb][kk] = *(const bf16x8*)&qp[kk * 32 + g * 8];
    }

    f32x4 o[2][4] = {};
    float mrow[2] = { NEG_INF, NEG_INF };
    float lrow[2] = { 0.f, 0.f };

    issueKV(0, 0);
    issueKV(1, 1);
    __syncthreads();

    int cur = 0;
    for (int t = 0; t < nt; ++t) {
      const bool last = (t == nt - 1);
      const bool pen  = (t == nt - 2);
      const bool do0  = !last;
      const int kv0 = t * KVB;
      const u16* lk = &smem[cur * LBUF16];

      // ---- QK^T (K-frags shared across qb) ----
      f32x4 s0[4] = {}, s1[4] = {};
      __builtin_amdgcn_s_setprio(1);
      #pragma unroll
      for (int c = 0; c < 4; ++c) {
        const int row = c * 16 + r;
        const int sw = (r & 7) << 3;
        bf16x8 kf0 = *(const bf16x8*)&lk[(row * 64 + g * 8) ^ sw];
        bf16x8 kf1 = *(const bf16x8*)&lk[(row * 64 + 32 + g * 8) ^ sw];
        if (do0) {
          s0[c] = __builtin_amdgcn_mfma_f32_16x16x32_bf16(kf0, qf[0][0], s0[c], 0, 0, 0);
          s0[c] = __builtin_amdgcn_mfma_f32_16x16x32_bf16(kf1, qf[0][1], s0[c], 0, 0, 0);
        }
        s1[c] = __builtin_amdgcn_mfma_f32_16x16x32_bf16(kf0, qf[1][0], s1[c], 0, 0, 0);
        s1[c] = __builtin_amdgcn_mfma_f32_16x16x32_bf16(kf1, qf[1][1], s1[c], 0, 0, 0);
      }
      __builtin_amdgcn_s_setprio(0);

      // ---- online softmax (log2 units), defer-max (T13) ----
      bf16x8 pf0[2], pf1[2];
      auto softmax = [&](f32x4* s, float& mref, float& lref, f32x4* ov,
                         bf16x8* pf, bool msk, int qg) {
        float pv[16];
        #pragma unroll
        for (int c = 0; c < 4; ++c)
          #pragma unroll
          for (int e = 0; e < 4; ++e) {
            float sv = s[c][e];
            if (msk) {
              int key = kv0 + c * 16 + g * 4 + e;
              if (key > qg) sv = NEG_INF;
            }
            pv[c * 4 + e] = sv;
          }
        float t8[8];
        #pragma unroll
        for (int i = 0; i < 8; ++i) t8[i] = fmaxf(pv[i], pv[i + 8]);
        #pragma unroll
        for (int i = 0; i < 4; ++i) t8[i] = fmaxf(t8[i], t8[i + 4]);
        float tm = fmaxf(fmaxf(t8[0], t8[1]), fmaxf(t8[2], t8[3]));
        tm = fmaxf(tm, __shfl_xor(tm, 16));
        tm = fmaxf(tm, __shfl_xor(tm, 32));
        if (__any(tm > mref + 8.0f)) {   // defer-max: P bounded by 2^8
          float mn = fmaxf(mref, tm);
          float corr = exp2_fast(mref - mn);
          lref *= corr;
          #pragma unroll
          for (int cd = 0; cd < 4; ++cd) ov[cd] *= corr;
          mref = mn;
        }
        #pragma unroll
        for (int i = 0; i < 16; ++i) pv[i] = exp2_fast(pv[i] - mref);
        float a8[8];
        #pragma unroll
        for (int i = 0; i < 8; ++i) a8[i] = pv[i] + pv[i + 8];
        #pragma unroll
        for (int i = 0; i < 4; ++i) a8[i] = a8[i] + a8[i + 4];
        float ps = (a8[0] + a8[1]) + (a8[2] + a8[3]);
        ps += __shfl_xor(ps, 16);
        ps += __shfl_xor(ps, 32);
        lref += ps;
        union { bf16x8 v; u32 w[4]; } u0, u1;
        #pragma unroll
        for (int k = 0; k < 4; ++k) {
          u0.w[k] = pk_bf16(pv[2 * k], pv[2 * k + 1]);
          u1.w[k] = pk_bf16(pv[8 + 2 * k], pv[9 + 2 * k]);
        }
        pf[0] = u0.v; pf[1] = u1.v;
      };
      if (do0) softmax(s0, mrow[0], lrow[0], o[0], pf0, pen, qg0);
      softmax(s1, mrow[1], lrow[1], o[1], pf1, last, qg0 + 64);

      // ---- PV via HW transpose reads (V shared across qb) ----
      bf16x4 tr[4][4];
      const u32 vb = (cur ? vls1 : vls0) + (u32)lane * 8;
      #pragma unroll
      for (int cd = 0; cd < 4; ++cd)
        #pragma unroll
        for (int kh = 0; kh < 4; ++kh)
          tr[cd][kh] = tr16(vb + cd * 2048 + kh * 512);
      asm volatile("s_waitcnt lgkmcnt(0)" ::: "memory");
      __builtin_amdgcn_sched_barrier(0);
      __builtin_amdgcn_s_setprio(1);
      #pragma unroll
      for (int cd = 0; cd < 4; ++cd) {
        #pragma unroll
        for (int ks = 0; ks < 2; ++ks) {
          bf16x4 lo = tr[cd][ks * 2], hi = tr[cd][ks * 2 + 1];
          bf16x8 av = { lo[0], lo[1], lo[2], lo[3], hi[0], hi[1], hi[2], hi[3] };
          if (do0) o[0][cd] = __builtin_amdgcn_mfma_f32_16x16x32_bf16(av, pf0[ks], o[0][cd], 0, 0, 0);
          o[1][cd] = __builtin_amdgcn_mfma_f32_16x16x32_bf16(av, pf1[ks], o[1][cd], 0, 0, 0);
        }
      }
      __builtin_amdgcn_s_setprio(0);

      __syncthreads();
      if (t + 2 < nt) issueKV(cur, t + 2);
      cur ^= 1;
    }

    // ---- epilogue: normalize + direct bf16 stores ----
    #pragma unroll
    for (int qb = 0; qb < 2; ++qb) {
      const float inv = 1.0f / lrow[qb];
      u16* op = aout + ((size_t)(b * TT) + qg0 + qb * 64) * DIM + h * HD;
      #pragma unroll
      for (int cd = 0; cd < 4; ++cd) {
        union { u16x4 v; u32 w[2]; } pk;
        pk.w[0] = pk_bf16(o[qb][cd][0] * inv, o[qb][cd][1] * inv);
        pk.w[1] = pk_bf16(o[qb][cd][2] * inv, o[qb][cd][3] * inv);
        *(u16x4*)&op[cd * 16 + g * 4] = pk.v;
      }
    }
  }
}

// ---------------- launcher ----------------
extern "C" void kernel_launch(void* const* d_in, const int* in_sizes, int n_in,
                              void* d_out, int out_size, void* d_ws, size_t ws_size,
                              hipStream_t stream) {
  const float* x    = (const float*)d_in[0];
  const float* Wqkv = (const float*)d_in[1];
  const float* bqkv = (const float*)d_in[2];
  const float* Wout = (const float*)d_in[3];
  const float* bout = (const float*)d_in[4];
  float* out = (float*)d_out;

  const int M = BB * TT;  // 8192
  u16* xb   = (u16*)d_ws;                      // [8192][1024]
  u16* wqt  = xb + (size_t)M * DIM;            // [3072][1024]
  u16* wot  = wqt + (size_t)3 * DIM * DIM;     // [1024][1024]
  u16* qkvb = wot + (size_t)DIM * DIM;         // [8192][3072]
  u16* aob  = qkvb + (size_t)M * 3 * DIM;      // [8192][1024]

  // conversions
  k_cvt<<<(M * DIM / 4 + 255) / 256, 256, 0, stream>>>(x, xb, M * DIM / 4);
  k_transpose<<<dim3(3 * DIM / 32, DIM / 32), 256, 0, stream>>>(Wqkv, wqt, DIM, 3 * DIM);
  k_transpose<<<dim3(DIM / 32, DIM / 32), 256, 0, stream>>>(Wout, wot, DIM, DIM);

  // qkv = x @ W_qkv + b_qkv  (bf16 out; Q columns pre-scaled by 0.125*log2e)
  k_gemm256<1><<<(M / 256) * (3 * DIM / 256), 512, 0, stream>>>(
      xb, wqt, bqkv, qkvb, nullptr, M, 3 * DIM, DIM, DIM, QSCALE, 3 * DIM / 256);

  // attention
  k_attn<<<BB * NH * 8, 256, 0, stream>>>(qkvb, aob);

  // out = attn_out @ W_out + b_out  (f32 out) — control on old 128^2 kernel
  k_gemm<0><<<dim3(DIM / 128, M / 128), 256, 0, stream>>>(
      aob, wot, bout, nullptr, out, M, DIM, DIM, 0, 1.0f);
}

// Round 5
// 169.473 us; speedup vs baseline: 1.0874x; 1.0874x over previous
//
#include <hip/hip_runtime.h>
#include <hip/hip_bf16.h>
#include <cstdint>
#include <cstddef>

#define DIM   1024
#define NH    16
#define HD    64
#define BB    4
#define TT    2048

typedef __attribute__((ext_vector_type(8))) short bf16x8;
typedef __attribute__((ext_vector_type(4))) short bf16x4;
typedef __attribute__((ext_vector_type(4))) float f32x4;
typedef __attribute__((ext_vector_type(4))) unsigned short u16x4;
typedef unsigned short u16;
typedef unsigned int u32;

#define NEG_INF (-__builtin_inff())
#define QSCALE 0.18033688011110543f  // 0.125 * log2(e): softmax becomes exp2
#define AS1 __attribute__((address_space(1)))
#define AS3 __attribute__((address_space(3)))

static __device__ __forceinline__ u16 f2bf(float f) {
  union { float f; unsigned u; } v; v.f = f;
  return (u16)((v.u + 0x7FFFu + ((v.u >> 16) & 1u)) >> 16);
}

static __device__ __forceinline__ u16 bfbits(float a) {
  union { __hip_bfloat16 h; u16 u; } c; c.h = __float2bfloat16(a); return c.u;
}
static __device__ __forceinline__ u32 pk_bf16(float a, float b) {
  return (u32)bfbits(a) | ((u32)bfbits(b) << 16);
}

static __device__ __forceinline__ float exp2_fast(float x) {
  float r;
  asm("v_exp_f32 %0, %1" : "=v"(r) : "v"(x));
  return r;
}

// HW transpose read: lane l receives column (l&15) of the 4x16 bf16 tile.
static __device__ __forceinline__ bf16x4 tr16(u32 byte_addr) {
  bf16x4 d;
  asm volatile("ds_read_b64_tr_b16 %0, %1" : "=v"(d) : "v"(byte_addr));
  return d;
}

#define MFMA16(A, B, C) __builtin_amdgcn_mfma_f32_16x16x32_bf16(A, B, C, 0, 0, 0)

// ---------------- elementwise f32 -> bf16 ----------------
__global__ __launch_bounds__(256) void k_cvt(const float* __restrict__ in,
                                             u16* __restrict__ out, int n4) {
  int i = blockIdx.x * 256 + threadIdx.x;
  if (i >= n4) return;
  float4 v = reinterpret_cast<const float4*>(in)[i];
  u16x4 o = { f2bf(v.x), f2bf(v.y), f2bf(v.z), f2bf(v.w) };
  *reinterpret_cast<u16x4*>(out + (size_t)i * 4) = o;
}

// ---------------- transpose f32[R][C] -> bf16[C][R] ----------------
__global__ __launch_bounds__(256) void k_transpose(const float* __restrict__ in,
                                                   u16* __restrict__ out,
                                                   int R, int C) {
  __shared__ float tile[32][33];
  int bx = blockIdx.x * 32;  // C dim
  int by = blockIdx.y * 32;  // R dim
  int tx = threadIdx.x & 31, ty = threadIdx.x >> 5;  // ty: 0..7
  #pragma unroll
  for (int i = 0; i < 32; i += 8)
    tile[ty + i][tx] = in[(size_t)(by + ty + i) * C + bx + tx];
  __syncthreads();
  #pragma unroll
  for (int i = 0; i < 32; i += 8)
    out[(size_t)(bx + ty + i) * R + by + tx] = f2bf(tile[tx][ty + i]);
}

// ======== 256x128 counted-vmcnt pipelined GEMM: C = A * Bt^T + bias ========
// BK=64, 8 waves (4M x 2N, per-wave 64x64), 512 thr.
// LDS: A triple-buffered (3 x 32KB), B double-buffered (2 x 16KB) = 128KB.
// 16KB half = [ks][row 128][64B], swizzle byte ^= ((byte>>9)&1)<<5 (0-conflict,
// verified R4), applied as inverse-swizzled global source (rule 21).
// Per K-tile, 2 phases:
//  P0: ds_read A f0,f1 + B c0..3 (12); stage A(t+2) -> Abuf[(t+2)%3] (4 loads)
//      [safe: that buf's last readers finished at tile t-1's trailing barrier]
//      barrier; MFMA rows 0-1 (16); barrier.
//  P1: ds_read A f2,f3 (4; B reused in regs); stage B(t+2) -> Bbuf[t&1]
//      [safe: B(t) reads all lgkm'd before mid-barrier]; barrier;
//      MFMA rows 2-3 (16); vmcnt(6) [= t+2's 6 loads in flight, t+1 landed];
//      barrier.
template <int OUT_BF16>
__global__ __launch_bounds__(512, 2) void k_gemm8p(const u16* __restrict__ A,
                                                   const u16* __restrict__ Bt,
                                                   const float* __restrict__ bias,
                                                   u16* __restrict__ Cb,
                                                   float* __restrict__ Cf,
                                                   int M, int N, int K,
                                                   int scale_cols, float scale,
                                                   int nbx) {
  __shared__ __align__(16) char lds[131072];

  const int tid = threadIdx.x;
  // bijective XCD swizzle (m204)
  const int nwg = gridDim.x;
  const int qq = nwg >> 3, rm = nwg & 7;
  const int xcd = blockIdx.x & 7, lidx = blockIdx.x >> 3;
  const int swz = (xcd < rm ? xcd * (qq + 1) : rm * (qq + 1) + (xcd - rm) * qq) + lidx;
  const int m0 = (swz / nbx) * 256, n0 = (swz % nbx) * 128;

  const int w = tid >> 6, lane = tid & 63;
  const int g = lane >> 4, r = lane & 15;
  const int wm = w >> 1, wn = w & 1;   // 4 M-waves x 2 N-waves

  f32x4 acc[4][4] = {};
  const int KT = K >> 6;

  // stage one 16KB half (128 rows x 64 k): 2 x global_load_lds per thread
  auto stageH = [&](char* base, const u16* src, int grow0, int kt) {
    #pragma unroll
    for (int i = 0; i < 2; ++i) {
      int o = (tid + i * 512) * 16;
      int l = o ^ (((o >> 9) & 1) << 5);
      int row = (l >> 6) & 127, ks = l >> 13, kb = l & 63;
      const u16* gp = src + (size_t)(grow0 + row) * K + kt * 64 + ks * 32 + (kb >> 1);
      __builtin_amdgcn_global_load_lds((const AS1 void*)gp, (AS3 void*)(base + o), 16, 0, 0);
    }
  };
  auto stageA = [&](int t) {   // 4 loads
    char* ab = lds + (t % 3) * 32768;
    stageH(ab, A, m0, t);
    stageH(ab + 16384, A, m0 + 128, t);
  };
  auto stageB = [&](int t) {   // 2 loads
    stageH(lds + 98304 + (t & 1) * 16384, Bt, n0, t);
  };

  auto ldAf = [&](int t, int f, bf16x8 (&dst)[2]) {
    const char* base = lds + (t % 3) * 32768 + (wm >> 1) * 16384;
    int rowb = ((wm & 1) * 64 + f * 16 + r) * 64 + g * 16;
    #pragma unroll
    for (int ks = 0; ks < 2; ++ks) {
      int l = ks * 8192 + rowb;
      dst[ks] = *(const bf16x8*)(base + (l ^ (((l >> 9) & 1) << 5)));
    }
  };
  auto ldBf = [&](int t, int c, bf16x8 (&dst)[2]) {
    const char* base = lds + 98304 + (t & 1) * 16384;
    int rowb = (wn * 64 + c * 16 + r) * 64 + g * 16;
    #pragma unroll
    for (int ks = 0; ks < 2; ++ks) {
      int l = ks * 8192 + rowb;
      dst[ks] = *(const bf16x8*)(base + (l ^ (((l >> 9) & 1) << 5)));
    }
  };

  // prologue: tiles 0,1 fully staged; t0 landed (vmcnt leaves t1's 6 in flight)
  stageA(0); stageB(0); stageA(1); stageB(1);
  asm volatile("s_waitcnt vmcnt(6)" ::: "memory");
  __builtin_amdgcn_s_barrier();

  for (int t = 0; t < KT; ++t) {
    const bool st = (t + 2 < KT);
    bf16x8 a0[2], a1[2], a2[2], a3[2], b0[2], b1[2], b2[2], b3[2];
    // ---- phase 0 ----
    ldAf(t, 0, a0); ldAf(t, 1, a1);
    ldBf(t, 0, b0); ldBf(t, 1, b1); ldBf(t, 2, b2); ldBf(t, 3, b3);
    if (st) stageA(t + 2);
    __builtin_amdgcn_s_barrier();
    __builtin_amdgcn_s_setprio(1);
    #pragma unroll
    for (int ks = 0; ks < 2; ++ks) {
      acc[0][0] = MFMA16(a0[ks], b0[ks], acc[0][0]);
      acc[0][1] = MFMA16(a0[ks], b1[ks], acc[0][1]);
      acc[0][2] = MFMA16(a0[ks], b2[ks], acc[0][2]);
      acc[0][3] = MFMA16(a0[ks], b3[ks], acc[0][3]);
      acc[1][0] = MFMA16(a1[ks], b0[ks], acc[1][0]);
      acc[1][1] = MFMA16(a1[ks], b1[ks], acc[1][1]);
      acc[1][2] = MFMA16(a1[ks], b2[ks], acc[1][2]);
      acc[1][3] = MFMA16(a1[ks], b3[ks], acc[1][3]);
    }
    __builtin_amdgcn_s_setprio(0);
    __builtin_amdgcn_s_barrier();
    // ---- phase 1 ----
    ldAf(t, 2, a2); ldAf(t, 3, a3);
    if (st) stageB(t + 2);
    __builtin_amdgcn_s_barrier();
    __builtin_amdgcn_s_setprio(1);
    #pragma unroll
    for (int ks = 0; ks < 2; ++ks) {
      acc[2][0] = MFMA16(a2[ks], b0[ks], acc[2][0]);
      acc[2][1] = MFMA16(a2[ks], b1[ks], acc[2][1]);
      acc[2][2] = MFMA16(a2[ks], b2[ks], acc[2][2]);
      acc[2][3] = MFMA16(a2[ks], b3[ks], acc[2][3]);
      acc[3][0] = MFMA16(a3[ks], b0[ks], acc[3][0]);
      acc[3][1] = MFMA16(a3[ks], b1[ks], acc[3][1]);
      acc[3][2] = MFMA16(a3[ks], b2[ks], acc[3][2]);
      acc[3][3] = MFMA16(a3[ks], b3[ks], acc[3][3]);
    }
    __builtin_amdgcn_s_setprio(0);
    if (st) asm volatile("s_waitcnt vmcnt(6)" ::: "memory");
    else    asm volatile("s_waitcnt vmcnt(0)" ::: "memory");
    __builtin_amdgcn_s_barrier();
  }

  // epilogue: row = m0+wm*64+f*16+g*4+e, col = n0+wn*64+c*16+r
  #pragma unroll
  for (int c = 0; c < 4; ++c) {
    int col = n0 + wn * 64 + c * 16 + r;
    float bv = bias[col];
    float sc = (col < scale_cols) ? scale : 1.0f;
    #pragma unroll
    for (int f = 0; f < 4; ++f) {
      #pragma unroll
      for (int e = 0; e < 4; ++e) {
        int row = m0 + wm * 64 + f * 16 + g * 4 + e;
        float val = (acc[f][c][e] + bv) * sc;
        if (OUT_BF16) Cb[(size_t)row * N + col] = f2bf(val);
        else          Cf[(size_t)row * N + col] = val;
      }
    }
  }
}

// ---------------- causal flash attention ----------------
#define KVB 64
#define LBUF16 8192   // u16 elems per buffer: K 4096 + V 4096

__global__ __launch_bounds__(256, 2) void k_attn(const u16* __restrict__ qkv,
                                                 u16* __restrict__ aout) {
  __shared__ __align__(16) u16 smem[2 * LBUF16];

  const int bid = blockIdx.x;
  const int swz = (bid & 7) * 64 + (bid >> 3);   // XCD swizzle (512 % 8 == 0)
  const int bh = swz >> 3;
  const int p = swz & 7;
  const int b = bh >> 4, h = bh & 15;
  const int tid = threadIdx.x, w = tid >> 6, lane = tid & 63;
  const int g = lane >> 4, r = lane & 15;

  const u32 vls0 = (u32)(uintptr_t)(AS3 u16*)(smem + 4096);
  const u32 vls1 = (u32)(uintptr_t)(AS3 u16*)(smem + LBUF16 + 4096);

  auto issueKV = [&](int buf, int t) {
    const int kv0 = t * KVB;
    u16* kb = &smem[buf * LBUF16];
    u16* vb = &smem[buf * LBUF16 + 4096];
    #pragma unroll
    for (int i = 0; i < 2; ++i) {
      int s = tid + 256 * i;
      int row = s >> 3, c8 = s & 7;
      int colg = c8 ^ (row & 7);   // pre-swizzled source, linear LDS dest
      const u16* gp = qkv + ((size_t)(b * TT) + kv0 + row) * (3 * DIM) + DIM + h * HD + colg * 8;
      __builtin_amdgcn_global_load_lds((const AS1 void*)gp,
                                       (AS3 void*)(kb + (size_t)s * 8), 16, 0, 0);
    }
    #pragma unroll
    for (int i = 0; i < 2; ++i) {
      int s = tid + 256 * i;
      int key = (s >> 1) & 63;
      int c = ((s >> 7) << 1) | (s & 1);
      const u16* gp = qkv + ((size_t)(b * TT) + kv0 + key) * (3 * DIM) + 2 * DIM + h * HD + c * 8;
      __builtin_amdgcn_global_load_lds((const AS1 void*)gp,
                                       (AS3 void*)(vb + (size_t)s * 8), 16, 0, 0);
    }
  };

  for (int half = 0; half < 2; ++half) {
    const int qt = half ? p : (15 - p);
    const int qbase = qt * 128;
    const int nt = 2 * qt + 2;
    const int qg0 = qbase + w * 16 + r;

    bf16x8 qf[2][2];
    #pragma unroll
    for (int qb = 0; qb < 2; ++qb) {
      const u16* qp = qkv + ((size_t)(b * TT) + qg0 + qb * 64) * (3 * DIM) + h * HD;
      #pragma unroll
      for (int kk = 0; kk < 2; ++kk)
        qf[qb][kk] = *(const bf16x8*)&qp[kk * 32 + g * 8];
    }

    f32x4 o[2][4] = {};
    float mrow[2] = { NEG_INF, NEG_INF };
    float lrow[2] = { 0.f, 0.f };

    issueKV(0, 0);
    issueKV(1, 1);
    __syncthreads();

    int cur = 0;
    for (int t = 0; t < nt; ++t) {
      const bool last = (t == nt - 1);
      const bool pen  = (t == nt - 2);
      const bool do0  = !last;
      const int kv0 = t * KVB;
      const u16* lk = &smem[cur * LBUF16];

      // ---- QK^T (K-frags shared across qb) ----
      f32x4 s0[4] = {}, s1[4] = {};
      __builtin_amdgcn_s_setprio(1);
      #pragma unroll
      for (int c = 0; c < 4; ++c) {
        const int row = c * 16 + r;
        const int sw = (r & 7) << 3;
        bf16x8 kf0 = *(const bf16x8*)&lk[(row * 64 + g * 8) ^ sw];
        bf16x8 kf1 = *(const bf16x8*)&lk[(row * 64 + 32 + g * 8) ^ sw];
        if (do0) {
          s0[c] = MFMA16(kf0, qf[0][0], s0[c]);
          s0[c] = MFMA16(kf1, qf[0][1], s0[c]);
        }
        s1[c] = MFMA16(kf0, qf[1][0], s1[c]);
        s1[c] = MFMA16(kf1, qf[1][1], s1[c]);
      }
      __builtin_amdgcn_s_setprio(0);

      // ---- online softmax (log2 units), defer-max (T13) ----
      bf16x8 pf0[2], pf1[2];
      auto softmax = [&](f32x4* s, float& mref, float& lref, f32x4* ov,
                         bf16x8* pf, bool msk, int qg) {
        float pv[16];
        #pragma unroll
        for (int c = 0; c < 4; ++c)
          #pragma unroll
          for (int e = 0; e < 4; ++e) {
            float sv = s[c][e];
            if (msk) {
              int key = kv0 + c * 16 + g * 4 + e;
              if (key > qg) sv = NEG_INF;
            }
            pv[c * 4 + e] = sv;
          }
        float t8[8];
        #pragma unroll
        for (int i = 0; i < 8; ++i) t8[i] = fmaxf(pv[i], pv[i + 8]);
        #pragma unroll
        for (int i = 0; i < 4; ++i) t8[i] = fmaxf(t8[i], t8[i + 4]);
        float tm = fmaxf(fmaxf(t8[0], t8[1]), fmaxf(t8[2], t8[3]));
        tm = fmaxf(tm, __shfl_xor(tm, 16));
        tm = fmaxf(tm, __shfl_xor(tm, 32));
        if (__any(tm > mref + 8.0f)) {   // defer-max: P bounded by 2^8
          float mn = fmaxf(mref, tm);
          float corr = exp2_fast(mref - mn);
          lref *= corr;
          #pragma unroll
          for (int cd = 0; cd < 4; ++cd) ov[cd] *= corr;
          mref = mn;
        }
        #pragma unroll
        for (int i = 0; i < 16; ++i) pv[i] = exp2_fast(pv[i] - mref);
        float a8[8];
        #pragma unroll
        for (int i = 0; i < 8; ++i) a8[i] = pv[i] + pv[i + 8];
        #pragma unroll
        for (int i = 0; i < 4; ++i) a8[i] = a8[i] + a8[i + 4];
        float ps = (a8[0] + a8[1]) + (a8[2] + a8[3]);
        ps += __shfl_xor(ps, 16);
        ps += __shfl_xor(ps, 32);
        lref += ps;
        union { bf16x8 v; u32 w[4]; } u0, u1;
        #pragma unroll
        for (int k = 0; k < 4; ++k) {
          u0.w[k] = pk_bf16(pv[2 * k], pv[2 * k + 1]);
          u1.w[k] = pk_bf16(pv[8 + 2 * k], pv[9 + 2 * k]);
        }
        pf[0] = u0.v; pf[1] = u1.v;
      };
      if (do0) softmax(s0, mrow[0], lrow[0], o[0], pf0, pen, qg0);
      softmax(s1, mrow[1], lrow[1], o[1], pf1, last, qg0 + 64);

      // ---- PV via HW transpose reads (V shared across qb) ----
      bf16x4 tr[4][4];
      const u32 vb = (cur ? vls1 : vls0) + (u32)lane * 8;
      #pragma unroll
      for (int cd = 0; cd < 4; ++cd)
        #pragma unroll
        for (int kh = 0; kh < 4; ++kh)
          tr[cd][kh] = tr16(vb + cd * 2048 + kh * 512);
      asm volatile("s_waitcnt lgkmcnt(0)" ::: "memory");
      __builtin_amdgcn_sched_barrier(0);
      __builtin_amdgcn_s_setprio(1);
      #pragma unroll
      for (int cd = 0; cd < 4; ++cd) {
        #pragma unroll
        for (int ks = 0; ks < 2; ++ks) {
          bf16x4 lo = tr[cd][ks * 2], hi = tr[cd][ks * 2 + 1];
          bf16x8 av = { lo[0], lo[1], lo[2], lo[3], hi[0], hi[1], hi[2], hi[3] };
          if (do0) o[0][cd] = MFMA16(av, pf0[ks], o[0][cd]);
          o[1][cd] = MFMA16(av, pf1[ks], o[1][cd]);
        }
      }
      __builtin_amdgcn_s_setprio(0);

      __syncthreads();
      if (t + 2 < nt) issueKV(cur, t + 2);
      cur ^= 1;
    }

    // ---- epilogue: normalize + direct bf16 stores ----
    #pragma unroll
    for (int qb = 0; qb < 2; ++qb) {
      const float inv = 1.0f / lrow[qb];
      u16* op = aout + ((size_t)(b * TT) + qg0 + qb * 64) * DIM + h * HD;
      #pragma unroll
      for (int cd = 0; cd < 4; ++cd) {
        union { u16x4 v; u32 w[2]; } pk;
        pk.w[0] = pk_bf16(o[qb][cd][0] * inv, o[qb][cd][1] * inv);
        pk.w[1] = pk_bf16(o[qb][cd][2] * inv, o[qb][cd][3] * inv);
        *(u16x4*)&op[cd * 16 + g * 4] = pk.v;
      }
    }
  }
}

// ---------------- launcher ----------------
extern "C" void kernel_launch(void* const* d_in, const int* in_sizes, int n_in,
                              void* d_out, int out_size, void* d_ws, size_t ws_size,
                              hipStream_t stream) {
  const float* x    = (const float*)d_in[0];
  const float* Wqkv = (const float*)d_in[1];
  const float* bqkv = (const float*)d_in[2];
  const float* Wout = (const float*)d_in[3];
  const float* bout = (const float*)d_in[4];
  float* out = (float*)d_out;

  const int M = BB * TT;  // 8192
  u16* xb   = (u16*)d_ws;                      // [8192][1024]
  u16* wqt  = xb + (size_t)M * DIM;            // [3072][1024]
  u16* wot  = wqt + (size_t)3 * DIM * DIM;     // [1024][1024]
  u16* qkvb = wot + (size_t)DIM * DIM;         // [8192][3072]
  u16* aob  = qkvb + (size_t)M * 3 * DIM;      // [8192][1024]

  // conversions
  k_cvt<<<(M * DIM / 4 + 255) / 256, 256, 0, stream>>>(x, xb, M * DIM / 4);
  k_transpose<<<dim3(3 * DIM / 32, DIM / 32), 256, 0, stream>>>(Wqkv, wqt, DIM, 3 * DIM);
  k_transpose<<<dim3(DIM / 32, DIM / 32), 256, 0, stream>>>(Wout, wot, DIM, DIM);

  // qkv = x @ W_qkv + b_qkv  (bf16 out; Q columns pre-scaled by 0.125*log2e)
  // grid 32x24 = 768 = 3 exact rounds of 256 CUs
  k_gemm8p<1><<<(M / 256) * (3 * DIM / 128), 512, 0, stream>>>(
      xb, wqt, bqkv, qkvb, nullptr, M, 3 * DIM, DIM, DIM, QSCALE, 3 * DIM / 128);

  // attention
  k_attn<<<BB * NH * 8, 256, 0, stream>>>(qkvb, aob);

  // out = attn_out @ W_out + b_out  (f32 out) — grid 32x8 = 256 = 1 exact round
  k_gemm8p<0><<<(M / 256) * (DIM / 128), 512, 0, stream>>>(
      aob, wot, bout, nullptr, out, M, DIM, DIM, 0, 1.0f, DIM / 128);
}